// Round 1
// baseline (726.614 us; speedup 1.0000x reference)
//
#include <hip/hip_runtime.h>
#include <hip/hip_bf16.h>

#define S_LEN 2048
#define NBATCH 4
#define DMODEL 1024
#define FDIM 64
#define NHEAD 16
#define BHEADS 64        // NBATCH*NHEAD
#define MROWS 8192       // S_LEN*NBATCH

typedef __attribute__((ext_vector_type(4))) float f32x4;
typedef __attribute__((ext_vector_type(8))) short s16x8;

static __device__ __forceinline__ unsigned short f2bf(float f) {
  union { float f; unsigned u; } v; v.f = f;
  unsigned r = v.u + 0x7fffu + ((v.u >> 16) & 1u);
  return (unsigned short)(r >> 16);
}

// ---------------- weight transpose + fp32->bf16 convert ----------------
// W: (K=1024, N=1024) fp32 row-major  ->  Wt: (N, K) bf16 row-major
__global__ __launch_bounds__(256) void transpose_w_kernel(
    const float* __restrict__ W, unsigned short* __restrict__ Wt) {
  __shared__ float tile[32][33];
  const int tx = threadIdx.x & 31, ty = threadIdx.x >> 5;
  const int bk = blockIdx.x * 32, bn = blockIdx.y * 32;
#pragma unroll
  for (int i = 0; i < 32; i += 8)
    tile[ty + i][tx] = W[(size_t)(bk + ty + i) * DMODEL + bn + tx];
  __syncthreads();
#pragma unroll
  for (int i = 0; i < 32; i += 8)
    Wt[(size_t)(bn + ty + i) * DMODEL + bk + tx] = f2bf(tile[tx][ty + i]);
}

// ---------------- GEMM: C = A(Mx1024 fp32) * Bt^T + bias ----------------
// Bt: (N=1024, K=1024) bf16 row-major (pre-transposed weight)
// MODE 0: out bf16, attention layout (b, s, f), value scaled by `scale`
// MODE 1: out bf16, transposed attention layout (b, f, s)
// MODE 2: out fp32, row-major (M, N)
template <int MODE>
__global__ __launch_bounds__(256, 2) void gemm_kernel(
    const float* __restrict__ A, const unsigned short* __restrict__ Bt,
    const float* __restrict__ bias, void* __restrict__ outp, float scale) {
  __shared__ unsigned short As[128 * 64];
  __shared__ unsigned short Bs[128 * 64];
  const int tid = threadIdx.x;
  const int lane = tid & 63;
  const int wm = (tid >> 7) & 1;  // wave row (2x2 wave grid)
  const int wn = (tid >> 6) & 1;  // wave col
  const int lg = lane >> 4;       // 0..3
  const int ll = lane & 15;
  const int m0 = blockIdx.x * 128;
  const int n0 = blockIdx.y * 128;

  f32x4 acc[4][4] = {};

  for (int kt = 0; kt < DMODEL; kt += 64) {
    // stage A tile (128 x 64), fp32 -> bf16, swizzled LDS
    {
      const int k4 = (tid & 15) << 2;
      const int r0 = tid >> 4;
#pragma unroll
      for (int p = 0; p < 8; ++p) {
        const int row = r0 + p * 16;
        const float4 a4 = *reinterpret_cast<const float4*>(
            &A[(size_t)(m0 + row) * DMODEL + kt + k4]);
        const unsigned lo = (unsigned)f2bf(a4.x) | ((unsigned)f2bf(a4.y) << 16);
        const unsigned hi = (unsigned)f2bf(a4.z) | ((unsigned)f2bf(a4.w) << 16);
        unsigned off = (unsigned)((row << 6) + k4) * 2u;
        off ^= (unsigned)(row & 7) << 4;
        uint2 val; val.x = lo; val.y = hi;
        *reinterpret_cast<uint2*>(reinterpret_cast<char*>(As) + off) = val;
      }
    }
    // stage B tile (128 x 64) bf16 copy, swizzled LDS
    {
      const int k8 = (tid & 7) << 3;
      const int r0 = tid >> 3;
#pragma unroll
      for (int p = 0; p < 4; ++p) {
        const int row = r0 + p * 32;
        const s16x8 b8 = *reinterpret_cast<const s16x8*>(
            &Bt[(size_t)(n0 + row) * DMODEL + kt + k8]);
        unsigned off = (unsigned)((row << 6) + k8) * 2u;
        off ^= (unsigned)(row & 7) << 4;
        *reinterpret_cast<s16x8*>(reinterpret_cast<char*>(Bs) + off) = b8;
      }
    }
    __syncthreads();
#pragma unroll
    for (int ks = 0; ks < 2; ++ks) {
      s16x8 af[4], bfr[4];
      const int kk = ks * 32 + (lg << 3);
#pragma unroll
      for (int mi = 0; mi < 4; ++mi) {
        const int row = wm * 64 + mi * 16 + ll;
        unsigned off = (unsigned)((row << 6) + kk) * 2u;
        off ^= (unsigned)(row & 7) << 4;
        af[mi] = *reinterpret_cast<const s16x8*>(
            reinterpret_cast<const char*>(As) + off);
      }
#pragma unroll
      for (int ni = 0; ni < 4; ++ni) {
        const int row = wn * 64 + ni * 16 + ll;
        unsigned off = (unsigned)((row << 6) + kk) * 2u;
        off ^= (unsigned)(row & 7) << 4;
        bfr[ni] = *reinterpret_cast<const s16x8*>(
            reinterpret_cast<const char*>(Bs) + off);
      }
#pragma unroll
      for (int mi = 0; mi < 4; ++mi)
#pragma unroll
        for (int ni = 0; ni < 4; ++ni)
          acc[mi][ni] = __builtin_amdgcn_mfma_f32_16x16x32_bf16(
              af[mi], bfr[ni], acc[mi][ni], 0, 0, 0);
    }
    __syncthreads();
  }

  // epilogue
#pragma unroll
  for (int mi = 0; mi < 4; ++mi) {
#pragma unroll
    for (int ni = 0; ni < 4; ++ni) {
      const int col = n0 + wn * 64 + ni * 16 + ll;
      const int rbase = m0 + wm * 64 + mi * 16 + (lg << 2);
      const float bcol = bias[col];
#pragma unroll
      for (int r = 0; r < 4; ++r) {
        const float v = (acc[mi][ni][r] + bcol) * scale;
        const int rr = rbase + r;
        if (MODE == 2) {
          reinterpret_cast<float*>(outp)[(size_t)rr * DMODEL + col] = v;
        } else {
          const int s = rr >> 2, n = rr & 3, h = col >> 6, f = col & 63;
          const int bh = n * NHEAD + h;
          int idx;
          if (MODE == 0) idx = bh * (S_LEN * FDIM) + s * FDIM + f;
          else           idx = bh * (S_LEN * FDIM) + f * S_LEN + s;
          reinterpret_cast<unsigned short*>(outp)[idx] = f2bf(v);
        }
      }
    }
  }
}

// ---------------- flash attention ----------------
// Q: (B, S, F) bf16, pre-scaled by 1/sqrt(F); Kt: (B, S, F) bf16;
// VT: (B, F, S) bf16; ctx: (MROWS, DMODEL) fp32 in (s*4+n, h*64+f) layout.
__global__ __launch_bounds__(256, 2) void attn_kernel(
    const unsigned short* __restrict__ Q, const unsigned short* __restrict__ Kt,
    const unsigned short* __restrict__ VT, float* __restrict__ ctx) {
  __shared__ unsigned short Ks[64 * 64];
  __shared__ unsigned short Vs[64 * 64];  // [f][kv]
  __shared__ unsigned short Ps[4][16 * 64];
  const int qt = blockIdx.x;
  const int b = blockIdx.y;
  const int tid = threadIdx.x;
  const int wave = tid >> 6, lane = tid & 63;
  const int lg = lane >> 4, ll = lane & 15;
  const int qrow0 = qt * 64 + wave * 16;

  // Q fragments held in registers for the whole kernel
  s16x8 qf[2];
  {
    const unsigned short* qp =
        &Q[((size_t)b * S_LEN + qrow0 + ll) * FDIM + (lg << 3)];
    qf[0] = *reinterpret_cast<const s16x8*>(qp);
    qf[1] = *reinterpret_cast<const s16x8*>(qp + 32);
  }

  float mrow[4], lrow[4];
  f32x4 o[4] = {};
#pragma unroll
  for (int r = 0; r < 4; ++r) { mrow[r] = -1e30f; lrow[r] = 0.f; }

  for (int kv0 = 0; kv0 < S_LEN; kv0 += 64) {
    // stage K (kv-major) and V (f-major, from pre-transposed VT), swizzled
    {
      const int c8 = (tid & 7) << 3;
      const int r0 = tid >> 3;
#pragma unroll
      for (int p = 0; p < 2; ++p) {
        const int row = r0 + p * 32;
        unsigned off = (unsigned)((row << 6) + c8) * 2u;
        off ^= (unsigned)(row & 7) << 4;
        const s16x8 k8 = *reinterpret_cast<const s16x8*>(
            &Kt[((size_t)b * S_LEN + kv0 + row) * FDIM + c8]);
        *reinterpret_cast<s16x8*>(reinterpret_cast<char*>(Ks) + off) = k8;
        const s16x8 v8 = *reinterpret_cast<const s16x8*>(
            &VT[((size_t)b * FDIM + row) * S_LEN + kv0 + c8]);
        *reinterpret_cast<s16x8*>(reinterpret_cast<char*>(Vs) + off) = v8;
      }
    }
    __syncthreads();

    // S = Q K^T : 16 x 64 per wave
    f32x4 sc[4];
#pragma unroll
    for (int ni = 0; ni < 4; ++ni) {
      const int row = ni * 16 + ll;  // kv index
      unsigned off0 = (unsigned)((row << 6) + (lg << 3)) * 2u;
      unsigned off1 = off0 + 64u;  // +32 bf16
      off0 ^= (unsigned)(row & 7) << 4;
      off1 ^= (unsigned)(row & 7) << 4;
      const s16x8 kb0 = *reinterpret_cast<const s16x8*>(
          reinterpret_cast<const char*>(Ks) + off0);
      const s16x8 kb1 = *reinterpret_cast<const s16x8*>(
          reinterpret_cast<const char*>(Ks) + off1);
      f32x4 z = {};
      z = __builtin_amdgcn_mfma_f32_16x16x32_bf16(qf[0], kb0, z, 0, 0, 0);
      sc[ni] = __builtin_amdgcn_mfma_f32_16x16x32_bf16(qf[1], kb1, z, 0, 0, 0);
    }

    // online softmax (rows live on 16-lane groups)
    float pm[4];
#pragma unroll
    for (int r = 0; r < 4; ++r)
      pm[r] = fmaxf(fmaxf(sc[0][r], sc[1][r]), fmaxf(sc[2][r], sc[3][r]));
#pragma unroll
    for (int r = 0; r < 4; ++r)
#pragma unroll
      for (int d = 1; d < 16; d <<= 1)
        pm[r] = fmaxf(pm[r], __shfl_xor(pm[r], d, 64));
    float fac[4], rs[4];
#pragma unroll
    for (int r = 0; r < 4; ++r) {
      const float mn = fmaxf(mrow[r], pm[r]);
      fac[r] = __expf(mrow[r] - mn);
      mrow[r] = mn;
      lrow[r] *= fac[r];
      rs[r] = 0.f;
    }
#pragma unroll
    for (int ni = 0; ni < 4; ++ni)
#pragma unroll
      for (int r = 0; r < 4; ++r) o[ni][r] *= fac[r];
    // P = exp(S - m), write transposed into per-wave LDS for the PV A-operand
#pragma unroll
    for (int ni = 0; ni < 4; ++ni) {
#pragma unroll
      for (int r = 0; r < 4; ++r) {
        const float p = __expf(sc[ni][r] - mrow[r]);
        rs[r] += p;
        const int row = (lg << 2) + r, col = ni * 16 + ll;
        unsigned off = (unsigned)((row << 6) + col) * 2u;
        off ^= (unsigned)(row & 7) << 4;
        *reinterpret_cast<unsigned short*>(
            reinterpret_cast<char*>(Ps[wave]) + off) = f2bf(p);
      }
    }
#pragma unroll
    for (int r = 0; r < 4; ++r) {
#pragma unroll
      for (int d = 1; d < 16; d <<= 1) rs[r] += __shfl_xor(rs[r], d, 64);
      lrow[r] += rs[r];
    }

    // O += P V
#pragma unroll
    for (int kk = 0; kk < 2; ++kk) {
      unsigned poff = (unsigned)((ll << 6) + kk * 32 + (lg << 3)) * 2u;
      poff ^= (unsigned)(ll & 7) << 4;
      const s16x8 pa = *reinterpret_cast<const s16x8*>(
          reinterpret_cast<const char*>(Ps[wave]) + poff);
#pragma unroll
      for (int ni = 0; ni < 4; ++ni) {
        const int row = ni * 16 + ll;  // f row in Vs
        unsigned off = (unsigned)((row << 6) + kk * 32 + (lg << 3)) * 2u;
        off ^= (unsigned)(row & 7) << 4;
        const s16x8 vb = *reinterpret_cast<const s16x8*>(
            reinterpret_cast<const char*>(Vs) + off);
        o[ni] = __builtin_amdgcn_mfma_f32_16x16x32_bf16(pa, vb, o[ni], 0, 0, 0);
      }
    }
    __syncthreads();
  }

  // normalize + write ctx in (s*4+n, h*64+f) fp32 layout
  const int n = b >> 4, h = b & 15;
#pragma unroll
  for (int r = 0; r < 4; ++r) {
    const float inv = 1.f / lrow[r];
    const int s = qrow0 + (lg << 2) + r;
#pragma unroll
    for (int ni = 0; ni < 4; ++ni) {
      const int f = ni * 16 + ll;
      ctx[(size_t)(s * NBATCH + n) * DMODEL + h * FDIM + f] = o[ni][r] * inv;
    }
  }
}

extern "C" void kernel_launch(void* const* d_in, const int* in_sizes, int n_in,
                              void* d_out, int out_size, void* d_ws,
                              size_t ws_size, hipStream_t stream) {
  const float* query = (const float*)d_in[0];
  const float* key_t = (const float*)d_in[1];
  const float* value = (const float*)d_in[2];
  const float* wq_w = (const float*)d_in[3];
  const float* wq_b = (const float*)d_in[4];
  const float* wk_w = (const float*)d_in[5];
  const float* wk_b = (const float*)d_in[6];
  const float* wv_w = (const float*)d_in[7];
  const float* wv_b = (const float*)d_in[8];
  const float* wo_w = (const float*)d_in[9];
  const float* wo_b = (const float*)d_in[10];

  char* ws = (char*)d_ws;
  unsigned short* wtq = (unsigned short*)(ws + (size_t)(0ull << 20));
  unsigned short* wtk = (unsigned short*)(ws + (size_t)(2ull << 20));
  unsigned short* wtv = (unsigned short*)(ws + (size_t)(4ull << 20));
  unsigned short* wto = (unsigned short*)(ws + (size_t)(6ull << 20));
  unsigned short* qa = (unsigned short*)(ws + (size_t)(8ull << 20));
  unsigned short* ka = (unsigned short*)(ws + (size_t)(24ull << 20));
  unsigned short* va = (unsigned short*)(ws + (size_t)(40ull << 20));
  float* ctx = (float*)(ws + (size_t)(56ull << 20));

  const dim3 blk(256);
  const dim3 tgrid(32, 32);
  hipLaunchKernelGGL(transpose_w_kernel, tgrid, blk, 0, stream, wq_w, wtq);
  hipLaunchKernelGGL(transpose_w_kernel, tgrid, blk, 0, stream, wk_w, wtk);
  hipLaunchKernelGGL(transpose_w_kernel, tgrid, blk, 0, stream, wv_w, wtv);
  hipLaunchKernelGGL(transpose_w_kernel, tgrid, blk, 0, stream, wo_w, wto);

  const dim3 ggrid(MROWS / 128, DMODEL / 128);
  hipLaunchKernelGGL((gemm_kernel<0>), ggrid, blk, 0, stream, query, wtq, wq_b,
                     (void*)qa, 0.125f);
  hipLaunchKernelGGL((gemm_kernel<0>), ggrid, blk, 0, stream, key_t, wtk, wk_b,
                     (void*)ka, 1.0f);
  hipLaunchKernelGGL((gemm_kernel<1>), ggrid, blk, 0, stream, value, wtv, wv_b,
                     (void*)va, 1.0f);

  const dim3 agrid(S_LEN / 64, BHEADS);
  hipLaunchKernelGGL(attn_kernel, agrid, blk, 0, stream, qa, ka, va, ctx);

  hipLaunchKernelGGL((gemm_kernel<2>), ggrid, blk, 0, stream, ctx, wto, wo_b,
                     d_out, 1.0f);
}

// Round 6
// 519.705 us; speedup vs baseline: 1.3981x; 1.3981x over previous
//
#include <hip/hip_runtime.h>
#include <hip/hip_bf16.h>

#define S_LEN 2048
#define NBATCH 4
#define DMODEL 1024
#define FDIM 64
#define NHEAD 16
#define BHEADS 64        // NBATCH*NHEAD
#define MROWS 8192       // S_LEN*NBATCH

typedef __attribute__((ext_vector_type(4))) float f32x4;
typedef __attribute__((ext_vector_type(8))) short s16x8;

static __device__ __forceinline__ unsigned short f2bf(float f) {
  union { float f; unsigned u; } v; v.f = f;
  unsigned r = v.u + 0x7fffu + ((v.u >> 16) & 1u);
  return (unsigned short)(r >> 16);
}

// async global->LDS, 16B per lane, wave-uniform LDS base + lane*16
#define GLD16(gaddr, laddr)                                            \
  __builtin_amdgcn_global_load_lds(                                    \
      (__attribute__((address_space(1))) void*)(void*)(gaddr),         \
      (__attribute__((address_space(3))) void*)(laddr), 16, 0, 0)

// ---------------- weight transpose + fp32->bf16 convert ----------------
// W: (K=1024, N=1024) fp32 row-major  ->  Wt: (N, K) bf16 row-major
__global__ __launch_bounds__(256) void transpose_w_kernel(
    const float* __restrict__ W, unsigned short* __restrict__ Wt) {
  __shared__ float tile[32][33];
  const int tx = threadIdx.x & 31, ty = threadIdx.x >> 5;
  const int bk = blockIdx.x * 32, bn = blockIdx.y * 32;
#pragma unroll
  for (int i = 0; i < 32; i += 8)
    tile[ty + i][tx] = W[(size_t)(bk + ty + i) * DMODEL + bn + tx];
  __syncthreads();
#pragma unroll
  for (int i = 0; i < 32; i += 8)
    Wt[(size_t)(bn + ty + i) * DMODEL + bk + tx] = f2bf(tile[tx][ty + i]);
}

// ---------------- fp32 -> bf16 convert (activations) ----------------
// 8 elements/thread, exact grid (no bounds check): 8192*1024 / (256*8) = 4096
__global__ __launch_bounds__(256) void convert_kernel(
    const float* __restrict__ in, unsigned short* __restrict__ out) {
  const size_t i = (size_t)blockIdx.x * 256 + threadIdx.x;
  const float4 a = ((const float4*)in)[2 * i];
  const float4 b = ((const float4*)in)[2 * i + 1];
  s16x8 o;
  o[0] = f2bf(a.x); o[1] = f2bf(a.y); o[2] = f2bf(a.z); o[3] = f2bf(a.w);
  o[4] = f2bf(b.x); o[5] = f2bf(b.y); o[6] = f2bf(b.z); o[7] = f2bf(b.w);
  ((s16x8*)out)[i] = o;
}

// ---------------- GEMM (m97 structure): C = A * Bt^T + bias ------------
// A:  (M=8192, K=1024) bf16 row-major
// Bt: (N=1024, K=1024) bf16 row-major (pre-transposed weight)
// MODE 0: out bf16, attention layout (b, s, f), value scaled by `scale`
// MODE 1: out bf16, transposed attention layout (b, f, s)
// MODE 2: out fp32, row-major (M, N)
template <int MODE>
__global__ __launch_bounds__(256, 2) void gemm_kernel(
    const unsigned short* __restrict__ A, const unsigned short* __restrict__ Bt,
    const float* __restrict__ bias, void* __restrict__ outp, float scale) {
  __shared__ unsigned short As[128 * 64];
  __shared__ unsigned short Bs[128 * 64];
  const int tid = threadIdx.x;
  const int lane = tid & 63;
  const int wv = tid >> 6;        // wave id 0..3
  const int wm = (tid >> 7) & 1;  // wave row (2x2 wave grid)
  const int wn = (tid >> 6) & 1;  // wave col
  const int lg = lane >> 4;       // 0..3
  const int ll = lane & 15;
  const int m0 = blockIdx.x * 128;
  const int n0 = blockIdx.y * 128;

  f32x4 acc[4][4] = {};

  // staging geometry: each wave stages 32 rows (4 calls x 8 rows) per operand
  // lane -> row (lane>>3), k-chunk (lane&7)*8 elems = *16 bytes
  const size_t lane_off =
      (size_t)(lane >> 3) * (DMODEL * 2) + (size_t)(lane & 7) * 16;
  const char* ag = (const char*)(A + (size_t)(m0 + wv * 32) * DMODEL) + lane_off;
  const char* bg = (const char*)(Bt + (size_t)(n0 + wv * 32) * DMODEL) + lane_off;
  char* al = (char*)As + wv * 32 * 128;
  char* bl = (char*)Bs + wv * 32 * 128;

  for (int kt = 0; kt < DMODEL; kt += 64) {
    const size_t kb = (size_t)kt * 2;
#pragma unroll
    for (int c = 0; c < 4; ++c) {
      GLD16(ag + kb + (size_t)c * 8 * DMODEL * 2, al + c * 8 * 128);
      GLD16(bg + kb + (size_t)c * 8 * DMODEL * 2, bl + c * 8 * 128);
    }
    __syncthreads();
#pragma unroll
    for (int ks = 0; ks < 2; ++ks) {
      const int kk = ks * 32 + (lg << 3);
      s16x8 af[4], bfr[4];
#pragma unroll
      for (int mi = 0; mi < 4; ++mi)
        af[mi] = *(const s16x8*)((const char*)As +
                                 (wm * 64 + mi * 16 + ll) * 128 + kk * 2);
#pragma unroll
      for (int ni = 0; ni < 4; ++ni)
        bfr[ni] = *(const s16x8*)((const char*)Bs +
                                  (wn * 64 + ni * 16 + ll) * 128 + kk * 2);
#pragma unroll
      for (int mi = 0; mi < 4; ++mi)
#pragma unroll
        for (int ni = 0; ni < 4; ++ni)
          acc[mi][ni] = __builtin_amdgcn_mfma_f32_16x16x32_bf16(
              af[mi], bfr[ni], acc[mi][ni], 0, 0, 0);
    }
    __syncthreads();
  }

  // epilogue
#pragma unroll
  for (int mi = 0; mi < 4; ++mi) {
#pragma unroll
    for (int ni = 0; ni < 4; ++ni) {
      const int col = n0 + wn * 64 + ni * 16 + ll;
      const int rbase = m0 + wm * 64 + mi * 16 + (lg << 2);
      const float bcol = bias[col];
#pragma unroll
      for (int r = 0; r < 4; ++r) {
        const float v = (acc[mi][ni][r] + bcol) * scale;
        const int rr = rbase + r;
        if (MODE == 2) {
          reinterpret_cast<float*>(outp)[(size_t)rr * DMODEL + col] = v;
        } else {
          const int s = rr >> 2, n = rr & 3, h = col >> 6, f = col & 63;
          const int bh = n * NHEAD + h;
          int idx;
          if (MODE == 0) idx = bh * (S_LEN * FDIM) + s * FDIM + f;
          else           idx = bh * (S_LEN * FDIM) + f * S_LEN + s;
          reinterpret_cast<unsigned short*>(outp)[idx] = f2bf(v);
        }
      }
    }
  }
}

// ---------------- flash attention ----------------
// Q: (B, S, F) bf16, pre-scaled by log2(e)/sqrt(F)  -> scores in log2 domain;
// Kt: (B, S, F) bf16; VT: (B, F, S) bf16;
// ctx: (MROWS, DMODEL) bf16 in (s*4+n, h*64+f) layout.
// Grid: 2048 flat blocks; XCD-chunked decode keeps one head's KV on one XCD.
__global__ __launch_bounds__(256, 2) void attn_kernel(
    const unsigned short* __restrict__ Q, const unsigned short* __restrict__ Kt,
    const unsigned short* __restrict__ VT, unsigned short* __restrict__ ctx) {
  __shared__ unsigned short Ks[64 * 64];
  __shared__ unsigned short Vs[64 * 64];  // [f][kv]
  __shared__ unsigned short Ps[4][16 * 64];
  // XCD-aware decode: flat = ((b&7)*32 + qt)*8 + (b>>3)  (bijective)
  const int flat = blockIdx.x;
  const int xcd = flat & 7;
  const int idx = flat >> 3;
  const int b = xcd * 8 + (idx >> 5);
  const int qt = idx & 31;
  const int tid = threadIdx.x;
  const int wave = tid >> 6, lane = tid & 63;
  const int lg = lane >> 4, ll = lane & 15;
  const int qrow0 = qt * 64 + wave * 16;

  // Q fragments held in registers for the whole kernel
  s16x8 qf[2];
  {
    const unsigned short* qp =
        &Q[((size_t)b * S_LEN + qrow0 + ll) * FDIM + (lg << 3)];
    qf[0] = *reinterpret_cast<const s16x8*>(qp);
    qf[1] = *reinterpret_cast<const s16x8*>(qp + 32);
  }

  // pre-swizzled per-lane source offset: LDS[row][L] <- glob[row][L ^ swz(row)]
  // row = base + (lane>>3), L = (lane&7)*16, swz = (row&7)<<4 = (lane>>3)<<4
  const unsigned sx =
      (((unsigned)lane & 7u) << 4) ^ (((unsigned)lane >> 3) << 4);
  const char* kbase = (const char*)Kt + (size_t)b * S_LEN * 128;
  const char* vbase = (const char*)VT + (size_t)b * FDIM * (S_LEN * 2);

  float mrow[4], lrow[4];
  f32x4 o[4] = {};
#pragma unroll
  for (int r = 0; r < 4; ++r) { mrow[r] = -1e30f; lrow[r] = 0.f; }

  for (int kv0 = 0; kv0 < S_LEN; kv0 += 64) {
    // stage K [kv][f] and V [f][kv-chunk] via global_load_lds (direct DMA),
    // swizzle applied through the pre-permuted global source address.
#pragma unroll
    for (int c = 0; c < 2; ++c) {
      const int rb = (wave * 2 + c) * 8;  // base row of this call's 8 rows
      GLD16(kbase + ((size_t)(kv0 + rb + (lane >> 3))) * 128 + sx,
            (char*)Ks + rb * 128);
      GLD16(vbase + ((size_t)(rb + (lane >> 3))) * (S_LEN * 2) +
                (size_t)kv0 * 2 + sx,
            (char*)Vs + rb * 128);
    }
    __syncthreads();

    // S = Q K^T : 16 x 64 per wave (scores already in log2 domain)
    f32x4 sc[4];
#pragma unroll
    for (int ni = 0; ni < 4; ++ni) {
      const int row = ni * 16 + ll;  // kv index
      unsigned off0 = (unsigned)((row << 6) + (lg << 3)) * 2u;
      unsigned off1 = off0 + 64u;  // +32 bf16
      off0 ^= (unsigned)(row & 7) << 4;
      off1 ^= (unsigned)(row & 7) << 4;
      const s16x8 kb0 = *reinterpret_cast<const s16x8*>(
          reinterpret_cast<const char*>(Ks) + off0);
      const s16x8 kb1 = *reinterpret_cast<const s16x8*>(
          reinterpret_cast<const char*>(Ks) + off1);
      f32x4 z = {};
      z = __builtin_amdgcn_mfma_f32_16x16x32_bf16(qf[0], kb0, z, 0, 0, 0);
      sc[ni] = __builtin_amdgcn_mfma_f32_16x16x32_bf16(qf[1], kb1, z, 0, 0, 0);
    }

    // online softmax in base-2 (rows live on 16-lane groups)
    float pm[4];
#pragma unroll
    for (int r = 0; r < 4; ++r)
      pm[r] = fmaxf(fmaxf(sc[0][r], sc[1][r]), fmaxf(sc[2][r], sc[3][r]));
#pragma unroll
    for (int r = 0; r < 4; ++r)
#pragma unroll
      for (int d = 1; d < 16; d <<= 1)
        pm[r] = fmaxf(pm[r], __shfl_xor(pm[r], d, 64));
    float fac[4], rs[4];
#pragma unroll
    for (int r = 0; r < 4; ++r) {
      const float mn = fmaxf(mrow[r], pm[r]);
      fac[r] = exp2f(mrow[r] - mn);
      mrow[r] = mn;
      lrow[r] *= fac[r];
      rs[r] = 0.f;
    }
#pragma unroll
    for (int ni = 0; ni < 4; ++ni)
#pragma unroll
      for (int r = 0; r < 4; ++r) o[ni][r] *= fac[r];
    // P = 2^(S - m), write transposed into per-wave LDS for the PV A-operand
#pragma unroll
    for (int ni = 0; ni < 4; ++ni) {
#pragma unroll
      for (int r = 0; r < 4; ++r) {
        const float p = exp2f(sc[ni][r] - mrow[r]);
        rs[r] += p;
        const int row = (lg << 2) + r, col = ni * 16 + ll;
        unsigned off = (unsigned)((row << 6) + col) * 2u;
        off ^= (unsigned)(row & 7) << 4;
        *reinterpret_cast<unsigned short*>(
            reinterpret_cast<char*>(Ps[wave]) + off) = f2bf(p);
      }
    }
#pragma unroll
    for (int r = 0; r < 4; ++r) {
#pragma unroll
      for (int d = 1; d < 16; d <<= 1) rs[r] += __shfl_xor(rs[r], d, 64);
      lrow[r] += rs[r];
    }

    // O += P V
#pragma unroll
    for (int kk = 0; kk < 2; ++kk) {
      unsigned poff = (unsigned)((ll << 6) + kk * 32 + (lg << 3)) * 2u;
      poff ^= (unsigned)(ll & 7) << 4;
      const s16x8 pa = *reinterpret_cast<const s16x8*>(
          reinterpret_cast<const char*>(Ps[wave]) + poff);
#pragma unroll
      for (int ni = 0; ni < 4; ++ni) {
        const int row = ni * 16 + ll;  // f row in Vs
        unsigned off = (unsigned)((row << 6) + kk * 32 + (lg << 3)) * 2u;
        off ^= (unsigned)(row & 7) << 4;
        const s16x8 vb = *reinterpret_cast<const s16x8*>(
            reinterpret_cast<const char*>(Vs) + off);
        o[ni] = __builtin_amdgcn_mfma_f32_16x16x32_bf16(pa, vb, o[ni], 0, 0, 0);
      }
    }
    __syncthreads();
  }

  // normalize + write ctx (bf16) in (s*4+n, h*64+f) layout
  const int n = b >> 4, h = b & 15;
#pragma unroll
  for (int r = 0; r < 4; ++r) {
    const float inv = 1.f / lrow[r];
    const int s = qrow0 + (lg << 2) + r;
#pragma unroll
    for (int ni = 0; ni < 4; ++ni) {
      const int f = ni * 16 + ll;
      ctx[(size_t)(s * NBATCH + n) * DMODEL + h * FDIM + f] =
          f2bf(o[ni][r] * inv);
    }
  }
}

extern "C" void kernel_launch(void* const* d_in, const int* in_sizes, int n_in,
                              void* d_out, int out_size, void* d_ws,
                              size_t ws_size, hipStream_t stream) {
  const float* query = (const float*)d_in[0];
  const float* key_t = (const float*)d_in[1];
  const float* value = (const float*)d_in[2];
  const float* wq_w = (const float*)d_in[3];
  const float* wq_b = (const float*)d_in[4];
  const float* wk_w = (const float*)d_in[5];
  const float* wk_b = (const float*)d_in[6];
  const float* wv_w = (const float*)d_in[7];
  const float* wv_b = (const float*)d_in[8];
  const float* wo_w = (const float*)d_in[9];
  const float* wo_b = (const float*)d_in[10];

  char* ws = (char*)d_ws;
  unsigned short* wtq = (unsigned short*)(ws + (0ull << 20));
  unsigned short* wtk = (unsigned short*)(ws + (2ull << 20));
  unsigned short* wtv = (unsigned short*)(ws + (4ull << 20));
  unsigned short* wto = (unsigned short*)(ws + (6ull << 20));
  unsigned short* cbuf = (unsigned short*)(ws + (8ull << 20));   // 16 MB, reused
  unsigned short* qa = (unsigned short*)(ws + (24ull << 20));
  unsigned short* ka = (unsigned short*)(ws + (40ull << 20));
  unsigned short* va = (unsigned short*)(ws + (56ull << 20));
  unsigned short* ctx = (unsigned short*)(ws + (72ull << 20));   // 16 MB bf16

  const dim3 blk(256);
  const dim3 tgrid(32, 32);
  hipLaunchKernelGGL(transpose_w_kernel, tgrid, blk, 0, stream, wq_w, wtq);
  hipLaunchKernelGGL(transpose_w_kernel, tgrid, blk, 0, stream, wk_w, wtk);
  hipLaunchKernelGGL(transpose_w_kernel, tgrid, blk, 0, stream, wv_w, wtv);
  hipLaunchKernelGGL(transpose_w_kernel, tgrid, blk, 0, stream, wo_w, wto);

  const dim3 ggrid(MROWS / 128, DMODEL / 128);
  const dim3 cgrid(4096);

  // Q pre-scale folds 1/sqrt(F) AND log2(e): softmax done in base-2 domain.
  const float qscale = 0.125f * 1.44269504088896340736f;

  hipLaunchKernelGGL(convert_kernel, cgrid, blk, 0, stream, query, cbuf);
  hipLaunchKernelGGL((gemm_kernel<0>), ggrid, blk, 0, stream, cbuf, wtq, wq_b,
                     (void*)qa, qscale);
  hipLaunchKernelGGL(convert_kernel, cgrid, blk, 0, stream, key_t, cbuf);
  hipLaunchKernelGGL((gemm_kernel<0>), ggrid, blk, 0, stream, cbuf, wtk, wk_b,
                     (void*)ka, 1.0f);
  hipLaunchKernelGGL(convert_kernel, cgrid, blk, 0, stream, value, cbuf);
  hipLaunchKernelGGL((gemm_kernel<1>), ggrid, blk, 0, stream, cbuf, wtv, wv_b,
                     (void*)va, 1.0f);

  const dim3 agrid(S_LEN / 64 * BHEADS);  // 2048 flat, XCD-decoded in-kernel
  hipLaunchKernelGGL(attn_kernel, agrid, blk, 0, stream, qa, ka, va, ctx);

  hipLaunchKernelGGL((gemm_kernel<2>), ggrid, blk, 0, stream, ctx, wto, wo_b,
                     d_out, 1.0f);
}

// Round 8
// 454.733 us; speedup vs baseline: 1.5979x; 1.1429x over previous
//
#include <hip/hip_runtime.h>
#include <hip/hip_bf16.h>

#define S_LEN 2048
#define NBATCH 4
#define DMODEL 1024
#define FDIM 64
#define NHEAD 16
#define BHEADS 64        // NBATCH*NHEAD
#define MROWS 8192       // S_LEN*NBATCH

typedef __attribute__((ext_vector_type(4))) float f32x4;
typedef __attribute__((ext_vector_type(8))) short s16x8;

static __device__ __forceinline__ unsigned short f2bf(float f) {
  union { float f; unsigned u; } v; v.f = f;
  unsigned r = v.u + 0x7fffu + ((v.u >> 16) & 1u);
  return (unsigned short)(r >> 16);
}

// pack two floats -> one u32 holding 2 bf16 (lo = a, hi = b)
static __device__ __forceinline__ unsigned pk2bf(float a, float b) {
  return (unsigned)f2bf(a) | ((unsigned)f2bf(b) << 16);
}

// async global->LDS, 16B per lane, wave-uniform LDS base + lane*16
#define GLD16(gaddr, laddr)                                            \
  __builtin_amdgcn_global_load_lds(                                    \
      (__attribute__((address_space(1))) void*)(void*)(gaddr),         \
      (__attribute__((address_space(3))) void*)(laddr), 16, 0, 0)

// ---------------- weight transpose + fp32->bf16 convert ----------------
// W: (K=1024, N=1024) fp32 row-major  ->  Wt: (N, K) bf16 row-major
__global__ __launch_bounds__(256) void transpose_w_kernel(
    const float* __restrict__ W, unsigned short* __restrict__ Wt) {
  __shared__ float tile[32][33];
  const int tx = threadIdx.x & 31, ty = threadIdx.x >> 5;
  const int bk = blockIdx.x * 32, bn = blockIdx.y * 32;
#pragma unroll
  for (int i = 0; i < 32; i += 8)
    tile[ty + i][tx] = W[(size_t)(bk + ty + i) * DMODEL + bn + tx];
  __syncthreads();
#pragma unroll
  for (int i = 0; i < 32; i += 8)
    Wt[(size_t)(bn + ty + i) * DMODEL + bk + tx] = f2bf(tile[tx][ty + i]);
}

// ---------------- fp32 -> bf16 convert (activations) ----------------
__global__ __launch_bounds__(256) void convert_kernel(
    const float* __restrict__ in, unsigned short* __restrict__ out) {
  const size_t i = (size_t)blockIdx.x * 256 + threadIdx.x;
  const float4 a = ((const float4*)in)[2 * i];
  const float4 b = ((const float4*)in)[2 * i + 1];
  s16x8 o;
  o[0] = f2bf(a.x); o[1] = f2bf(a.y); o[2] = f2bf(a.z); o[3] = f2bf(a.w);
  o[4] = f2bf(b.x); o[5] = f2bf(b.y); o[6] = f2bf(b.z); o[7] = f2bf(b.w);
  ((s16x8*)out)[i] = o;
}

// ---------------- GEMM (m97 structure): C = A * Bt^T + bias ------------
template <int MODE>
__global__ __launch_bounds__(256, 2) void gemm_kernel(
    const unsigned short* __restrict__ A, const unsigned short* __restrict__ Bt,
    const float* __restrict__ bias, void* __restrict__ outp, float scale) {
  __shared__ unsigned short As[128 * 64];
  __shared__ unsigned short Bs[128 * 64];
  const int tid = threadIdx.x;
  const int lane = tid & 63;
  const int wv = tid >> 6;        // wave id 0..3
  const int wm = (tid >> 7) & 1;  // wave row (2x2 wave grid)
  const int wn = (tid >> 6) & 1;  // wave col
  const int lg = lane >> 4;       // 0..3
  const int ll = lane & 15;
  const int m0 = blockIdx.x * 128;
  const int n0 = blockIdx.y * 128;

  f32x4 acc[4][4] = {};

  const size_t lane_off =
      (size_t)(lane >> 3) * (DMODEL * 2) + (size_t)(lane & 7) * 16;
  const char* ag = (const char*)(A + (size_t)(m0 + wv * 32) * DMODEL) + lane_off;
  const char* bg = (const char*)(Bt + (size_t)(n0 + wv * 32) * DMODEL) + lane_off;
  char* al = (char*)As + wv * 32 * 128;
  char* bl = (char*)Bs + wv * 32 * 128;

  for (int kt = 0; kt < DMODEL; kt += 64) {
    const size_t kb = (size_t)kt * 2;
#pragma unroll
    for (int c = 0; c < 4; ++c) {
      GLD16(ag + kb + (size_t)c * 8 * DMODEL * 2, al + c * 8 * 128);
      GLD16(bg + kb + (size_t)c * 8 * DMODEL * 2, bl + c * 8 * 128);
    }
    __syncthreads();
#pragma unroll
    for (int ks = 0; ks < 2; ++ks) {
      const int kk = ks * 32 + (lg << 3);
      s16x8 af[4], bfr[4];
#pragma unroll
      for (int mi = 0; mi < 4; ++mi)
        af[mi] = *(const s16x8*)((const char*)As +
                                 (wm * 64 + mi * 16 + ll) * 128 + kk * 2);
#pragma unroll
      for (int ni = 0; ni < 4; ++ni)
        bfr[ni] = *(const s16x8*)((const char*)Bs +
                                  (wn * 64 + ni * 16 + ll) * 128 + kk * 2);
#pragma unroll
      for (int mi = 0; mi < 4; ++mi)
#pragma unroll
        for (int ni = 0; ni < 4; ++ni)
          acc[mi][ni] = __builtin_amdgcn_mfma_f32_16x16x32_bf16(
              af[mi], bfr[ni], acc[mi][ni], 0, 0, 0);
    }
    __syncthreads();
  }

#pragma unroll
  for (int mi = 0; mi < 4; ++mi) {
#pragma unroll
    for (int ni = 0; ni < 4; ++ni) {
      const int col = n0 + wn * 64 + ni * 16 + ll;
      const int rbase = m0 + wm * 64 + mi * 16 + (lg << 2);
      const float bcol = bias[col];
#pragma unroll
      for (int r = 0; r < 4; ++r) {
        const float v = (acc[mi][ni][r] + bcol) * scale;
        const int rr = rbase + r;
        if (MODE == 2) {
          reinterpret_cast<float*>(outp)[(size_t)rr * DMODEL + col] = v;
        } else {
          const int s = rr >> 2, n = rr & 3, h = col >> 6, f = col & 63;
          const int bh = n * NHEAD + h;
          int idx;
          if (MODE == 0) idx = bh * (S_LEN * FDIM) + s * FDIM + f;
          else           idx = bh * (S_LEN * FDIM) + f * S_LEN + s;
          reinterpret_cast<unsigned short*>(outp)[idx] = f2bf(v);
        }
      }
    }
  }
}

// ---------------- flash attention (swapped-QK^T, in-register softmax) ----
// Q: (B, S, F) bf16, pre-scaled by log2(e)/sqrt(F); Kt: (B, S, F) bf16;
// VT: (B, F, S) bf16; ctx: (MROWS, DMODEL) bf16 in (s*4+n, h*64+f) layout.
// Per wave: 16 q-rows. mfma(K,Q) gives S^T[kv][q]: q = ll (lane&15) fixed per
// lane -> running max/sum are SCALARS per lane; P stays in registers.
__global__ __launch_bounds__(256, 2) void attn_kernel(
    const unsigned short* __restrict__ Q, const unsigned short* __restrict__ Kt,
    const unsigned short* __restrict__ VT, unsigned short* __restrict__ ctx) {
  __shared__ unsigned short Ks[64 * 64];
  __shared__ unsigned short Vs[64 * 64];  // [f][kv]
  // XCD-aware decode: flat = ((b&7)*32 + qt)*8 + (b>>3)  (bijective)
  const int flat = blockIdx.x;
  const int xcd = flat & 7;
  const int idx = flat >> 3;
  const int b = xcd * 8 + (idx >> 5);
  const int qt = idx & 31;
  const int tid = threadIdx.x;
  const int wave = tid >> 6, lane = tid & 63;
  const int lg = lane >> 4, ll = lane & 15;
  const int qrow0 = qt * 64 + wave * 16;

  // Q fragments (B-operand of swapped QK^T; same per-lane layout as before)
  s16x8 qf[2];
  {
    const unsigned short* qp =
        &Q[((size_t)b * S_LEN + qrow0 + ll) * FDIM + (lg << 3)];
    qf[0] = *reinterpret_cast<const s16x8*>(qp);
    qf[1] = *reinterpret_cast<const s16x8*>(qp + 32);
  }

  // pre-swizzled per-lane source offset: LDS[row][L] <- glob[row][L ^ swz(row)]
  const unsigned sx =
      (((unsigned)lane & 7u) << 4) ^ (((unsigned)lane >> 3) << 4);
  const char* kbase = (const char*)Kt + (size_t)b * S_LEN * 128;
  const char* vbase = (const char*)VT + (size_t)b * FDIM * (S_LEN * 2);

  float m_run = -1e30f, l_run = 0.f;
  f32x4 o[4] = {};  // O^T[f = ni*16 + lg*4 + r][q = ll]

  const int shfl_base = ((lg & 1) << 5) + ll;  // source lane for kv regroup
  const bool sel_hi = (lg >> 1) != 0;

  for (int kv0 = 0; kv0 < S_LEN; kv0 += 64) {
    // stage K [kv][f] and V [f][kv-chunk] via global_load_lds (direct DMA)
#pragma unroll
    for (int c = 0; c < 2; ++c) {
      const int rb = (wave * 2 + c) * 8;
      GLD16(kbase + ((size_t)(kv0 + rb + (lane >> 3))) * 128 + sx,
            (char*)Ks + rb * 128);
      GLD16(vbase + ((size_t)(rb + (lane >> 3))) * (S_LEN * 2) +
                (size_t)kv0 * 2 + sx,
            (char*)Vs + rb * 128);
    }
    __syncthreads();

    // S^T = K Q^T : sc[ni][r] = S^T[kv = ni*16 + lg*4 + r][q = ll]
    f32x4 sc[4];
#pragma unroll
    for (int ni = 0; ni < 4; ++ni) {
      const int row = ni * 16 + ll;  // kv row of K
      unsigned off0 = (unsigned)((row << 6) + (lg << 3)) * 2u;
      unsigned off1 = off0 + 64u;
      off0 ^= (unsigned)(row & 7) << 4;
      off1 ^= (unsigned)(row & 7) << 4;
      const s16x8 kb0 = *reinterpret_cast<const s16x8*>(
          reinterpret_cast<const char*>(Ks) + off0);
      const s16x8 kb1 = *reinterpret_cast<const s16x8*>(
          reinterpret_cast<const char*>(Ks) + off1);
      f32x4 z = {};
      z = __builtin_amdgcn_mfma_f32_16x16x32_bf16(kb0, qf[0], z, 0, 0, 0);
      sc[ni] = __builtin_amdgcn_mfma_f32_16x16x32_bf16(kb1, qf[1], z, 0, 0, 0);
    }

    // ---- in-register online softmax (scalar m/l per lane; q = ll) ----
    float pm0 = fmaxf(fmaxf(sc[0][0], sc[0][1]), fmaxf(sc[0][2], sc[0][3]));
    float pm1 = fmaxf(fmaxf(sc[1][0], sc[1][1]), fmaxf(sc[1][2], sc[1][3]));
    float pm2 = fmaxf(fmaxf(sc[2][0], sc[2][1]), fmaxf(sc[2][2], sc[2][3]));
    float pm3 = fmaxf(fmaxf(sc[3][0], sc[3][1]), fmaxf(sc[3][2], sc[3][3]));
    float pm = fmaxf(fmaxf(pm0, pm1), fmaxf(pm2, pm3));
    pm = fmaxf(pm, __shfl_xor(pm, 16, 64));
    pm = fmaxf(pm, __shfl_xor(pm, 32, 64));
    const float mn = fmaxf(m_run, pm);
    const float fac = exp2f(m_run - mn);
    m_run = mn;

    float rs = 0.f;
#pragma unroll
    for (int ni = 0; ni < 4; ++ni)
#pragma unroll
      for (int r = 0; r < 4; ++r) {
        const float p = exp2f(sc[ni][r] - mn);
        sc[ni][r] = p;
        rs += p;
      }
    rs += __shfl_xor(rs, 16, 64);
    rs += __shfl_xor(rs, 32, 64);
    l_run = l_run * fac + rs;
#pragma unroll
    for (int ni = 0; ni < 4; ++ni)
#pragma unroll
      for (int r = 0; r < 4; ++r) o[ni][r] *= fac;

    // pack P to bf16 pairs: pk[ni][w] = (kv = ni*16+lg*4+2w, +1) for q = ll
    unsigned pk[4][2];
#pragma unroll
    for (int ni = 0; ni < 4; ++ni) {
      pk[ni][0] = pk2bf(sc[ni][0], sc[ni][1]);
      pk[ni][1] = pk2bf(sc[ni][2], sc[ni][3]);
    }

    // O^T += V^T P : per kk (kv half), regroup kv 4s -> 8s across lg groups
#pragma unroll
    for (int kk = 0; kk < 2; ++kk) {
      const int nb = 2 * kk;
      const unsigned a0 = __shfl(pk[nb][0], shfl_base, 64);
      const unsigned a1 = __shfl(pk[nb][1], shfl_base, 64);
      const unsigned c0 = __shfl(pk[nb + 1][0], shfl_base, 64);
      const unsigned c1 = __shfl(pk[nb + 1][1], shfl_base, 64);
      const unsigned b0 = __shfl(pk[nb][0], shfl_base + 16, 64);
      const unsigned b1 = __shfl(pk[nb][1], shfl_base + 16, 64);
      const unsigned d0 = __shfl(pk[nb + 1][0], shfl_base + 16, 64);
      const unsigned d1 = __shfl(pk[nb + 1][1], shfl_base + 16, 64);
      union { s16x8 v; unsigned u[4]; } pb;
      pb.u[0] = sel_hi ? c0 : a0;
      pb.u[1] = sel_hi ? c1 : a1;
      pb.u[2] = sel_hi ? d0 : b0;
      pb.u[3] = sel_hi ? d1 : b1;
#pragma unroll
      for (int ni = 0; ni < 4; ++ni) {
        const int row = ni * 16 + ll;  // f row in Vs
        unsigned off = (unsigned)((row << 6) + kk * 32 + (lg << 3)) * 2u;
        off ^= (unsigned)(row & 7) << 4;
        const s16x8 vb = *reinterpret_cast<const s16x8*>(
            reinterpret_cast<const char*>(Vs) + off);
        o[ni] = __builtin_amdgcn_mfma_f32_16x16x32_bf16(vb, pb.v, o[ni], 0, 0, 0);
      }
    }
    __syncthreads();
  }

  // normalize + write ctx (bf16): q = qrow0 + ll, f = ni*16 + lg*4 + r
  const int n = b >> 4, h = b & 15;
  const float inv = 1.f / l_run;
  const int s = qrow0 + ll;
  unsigned short* crow = ctx + (size_t)(s * NBATCH + n) * DMODEL + h * FDIM;
#pragma unroll
  for (int ni = 0; ni < 4; ++ni) {
    ushort4 w;
    w.x = f2bf(o[ni][0] * inv);
    w.y = f2bf(o[ni][1] * inv);
    w.z = f2bf(o[ni][2] * inv);
    w.w = f2bf(o[ni][3] * inv);
    *reinterpret_cast<ushort4*>(crow + ni * 16 + lg * 4) = w;
  }
}

extern "C" void kernel_launch(void* const* d_in, const int* in_sizes, int n_in,
                              void* d_out, int out_size, void* d_ws,
                              size_t ws_size, hipStream_t stream) {
  const float* query = (const float*)d_in[0];
  const float* key_t = (const float*)d_in[1];
  const float* value = (const float*)d_in[2];
  const float* wq_w = (const float*)d_in[3];
  const float* wq_b = (const float*)d_in[4];
  const float* wk_w = (const float*)d_in[5];
  const float* wk_b = (const float*)d_in[6];
  const float* wv_w = (const float*)d_in[7];
  const float* wv_b = (const float*)d_in[8];
  const float* wo_w = (const float*)d_in[9];
  const float* wo_b = (const float*)d_in[10];

  char* ws = (char*)d_ws;
  unsigned short* wtq = (unsigned short*)(ws + (0ull << 20));
  unsigned short* wtk = (unsigned short*)(ws + (2ull << 20));
  unsigned short* wtv = (unsigned short*)(ws + (4ull << 20));
  unsigned short* wto = (unsigned short*)(ws + (6ull << 20));
  unsigned short* cbuf = (unsigned short*)(ws + (8ull << 20));   // 16 MB, reused
  unsigned short* qa = (unsigned short*)(ws + (24ull << 20));
  unsigned short* ka = (unsigned short*)(ws + (40ull << 20));
  unsigned short* va = (unsigned short*)(ws + (56ull << 20));
  unsigned short* ctx = (unsigned short*)(ws + (72ull << 20));   // 16 MB bf16

  const dim3 blk(256);
  const dim3 tgrid(32, 32);
  hipLaunchKernelGGL(transpose_w_kernel, tgrid, blk, 0, stream, wq_w, wtq);
  hipLaunchKernelGGL(transpose_w_kernel, tgrid, blk, 0, stream, wk_w, wtk);
  hipLaunchKernelGGL(transpose_w_kernel, tgrid, blk, 0, stream, wv_w, wtv);
  hipLaunchKernelGGL(transpose_w_kernel, tgrid, blk, 0, stream, wo_w, wto);

  const dim3 ggrid(MROWS / 128, DMODEL / 128);
  const dim3 cgrid(4096);

  // Q pre-scale folds 1/sqrt(F) AND log2(e): softmax done in base-2 domain.
  const float qscale = 0.125f * 1.44269504088896340736f;

  hipLaunchKernelGGL(convert_kernel, cgrid, blk, 0, stream, query, cbuf);
  hipLaunchKernelGGL((gemm_kernel<0>), ggrid, blk, 0, stream, cbuf, wtq, wq_b,
                     (void*)qa, qscale);
  hipLaunchKernelGGL(convert_kernel, cgrid, blk, 0, stream, key_t, cbuf);
  hipLaunchKernelGGL((gemm_kernel<0>), ggrid, blk, 0, stream, cbuf, wtk, wk_b,
                     (void*)ka, 1.0f);
  hipLaunchKernelGGL(convert_kernel, cgrid, blk, 0, stream, value, cbuf);
  hipLaunchKernelGGL((gemm_kernel<1>), ggrid, blk, 0, stream, cbuf, wtv, wv_b,
                     (void*)va, 1.0f);

  const dim3 agrid(S_LEN / 64 * BHEADS);  // 2048 flat, XCD-decoded in-kernel
  hipLaunchKernelGGL(attn_kernel, agrid, blk, 0, stream, qa, ka, va, ctx);

  hipLaunchKernelGGL((gemm_kernel<2>), ggrid, blk, 0, stream, ctx, wto, wo_b,
                     d_out, 1.0f);
}

// Round 12
// 442.176 us; speedup vs baseline: 1.6433x; 1.0284x over previous
//
#include <hip/hip_runtime.h>
#include <hip/hip_bf16.h>

#define S_LEN 2048
#define NBATCH 4
#define DMODEL 1024
#define FDIM 64
#define NHEAD 16
#define BHEADS 64        // NBATCH*NHEAD
#define MROWS 8192       // S_LEN*NBATCH

typedef __attribute__((ext_vector_type(4))) float f32x4;
typedef __attribute__((ext_vector_type(8))) short s16x8;
typedef __attribute__((ext_vector_type(4))) short s16x4;

static __device__ __forceinline__ unsigned short f2bf(float f) {
  union { float f; unsigned u; } v; v.f = f;
  unsigned r = v.u + 0x7fffu + ((v.u >> 16) & 1u);
  return (unsigned short)(r >> 16);
}

// pack two floats -> one u32 holding 2 bf16 (lo = a, hi = b)  [verified R8]
static __device__ __forceinline__ unsigned pk2bf(float a, float b) {
  return (unsigned)f2bf(a) | ((unsigned)f2bf(b) << 16);
}

// async global->LDS, 16B per lane, wave-uniform LDS base + lane*16
#define GLD16(gaddr, laddr)                                            \
  __builtin_amdgcn_global_load_lds(                                    \
      (__attribute__((address_space(1))) void*)(void*)(gaddr),         \
      (__attribute__((address_space(3))) void*)(laddr), 16, 0, 0)

// ---------------- weight transpose + fp32->bf16 convert ----------------
__global__ __launch_bounds__(256) void transpose_w_kernel(
    const float* __restrict__ W, unsigned short* __restrict__ Wt) {
  __shared__ float tile[32][33];
  const int tx = threadIdx.x & 31, ty = threadIdx.x >> 5;
  const int bk = blockIdx.x * 32, bn = blockIdx.y * 32;
#pragma unroll
  for (int i = 0; i < 32; i += 8)
    tile[ty + i][tx] = W[(size_t)(bk + ty + i) * DMODEL + bn + tx];
  __syncthreads();
#pragma unroll
  for (int i = 0; i < 32; i += 8)
    Wt[(size_t)(bn + ty + i) * DMODEL + bk + tx] = f2bf(tile[tx][ty + i]);
}

// ---------------- fp32 -> bf16 convert (activations) ----------------
__global__ __launch_bounds__(256) void convert_kernel(
    const float* __restrict__ in, unsigned short* __restrict__ out) {
  const size_t i = (size_t)blockIdx.x * 256 + threadIdx.x;
  const float4 a = ((const float4*)in)[2 * i];
  const float4 b = ((const float4*)in)[2 * i + 1];
  s16x8 o;
  o[0] = f2bf(a.x); o[1] = f2bf(a.y); o[2] = f2bf(a.z); o[3] = f2bf(a.w);
  o[4] = f2bf(b.x); o[5] = f2bf(b.y); o[6] = f2bf(b.z); o[7] = f2bf(b.w);
  ((s16x8*)out)[i] = o;
}

// ---------------- GEMM (m97 structure): C = A * Bt^T + bias ------------
template <int MODE>
__global__ __launch_bounds__(256, 2) void gemm_kernel(
    const unsigned short* __restrict__ A, const unsigned short* __restrict__ Bt,
    const float* __restrict__ bias, void* __restrict__ outp, float scale) {
  __shared__ unsigned short As[128 * 64];
  __shared__ unsigned short Bs[128 * 64];
  const int tid = threadIdx.x;
  const int lane = tid & 63;
  const int wv = tid >> 6;        // wave id 0..3
  const int wm = (tid >> 7) & 1;  // wave row (2x2 wave grid)
  const int wn = (tid >> 6) & 1;  // wave col
  const int lg = lane >> 4;       // 0..3
  const int ll = lane & 15;
  const int m0 = blockIdx.x * 128;
  const int n0 = blockIdx.y * 128;

  f32x4 acc[4][4] = {};

  const size_t lane_off =
      (size_t)(lane >> 3) * (DMODEL * 2) + (size_t)(lane & 7) * 16;
  const char* ag = (const char*)(A + (size_t)(m0 + wv * 32) * DMODEL) + lane_off;
  const char* bg = (const char*)(Bt + (size_t)(n0 + wv * 32) * DMODEL) + lane_off;
  char* al = (char*)As + wv * 32 * 128;
  char* bl = (char*)Bs + wv * 32 * 128;

  for (int kt = 0; kt < DMODEL; kt += 64) {
    const size_t kb = (size_t)kt * 2;
#pragma unroll
    for (int c = 0; c < 4; ++c) {
      GLD16(ag + kb + (size_t)c * 8 * DMODEL * 2, al + c * 8 * 128);
      GLD16(bg + kb + (size_t)c * 8 * DMODEL * 2, bl + c * 8 * 128);
    }
    __syncthreads();
#pragma unroll
    for (int ks = 0; ks < 2; ++ks) {
      const int kk = ks * 32 + (lg << 3);
      s16x8 af[4], bfr[4];
#pragma unroll
      for (int mi = 0; mi < 4; ++mi)
        af[mi] = *(const s16x8*)((const char*)As +
                                 (wm * 64 + mi * 16 + ll) * 128 + kk * 2);
#pragma unroll
      for (int ni = 0; ni < 4; ++ni)
        bfr[ni] = *(const s16x8*)((const char*)Bs +
                                  (wn * 64 + ni * 16 + ll) * 128 + kk * 2);
#pragma unroll
      for (int mi = 0; mi < 4; ++mi)
#pragma unroll
        for (int ni = 0; ni < 4; ++ni)
          acc[mi][ni] = __builtin_amdgcn_mfma_f32_16x16x32_bf16(
              af[mi], bfr[ni], acc[mi][ni], 0, 0, 0);
    }
    __syncthreads();
  }

#pragma unroll
  for (int mi = 0; mi < 4; ++mi) {
#pragma unroll
    for (int ni = 0; ni < 4; ++ni) {
      const int col = n0 + wn * 64 + ni * 16 + ll;
      const int rbase = m0 + wm * 64 + mi * 16 + (lg << 2);
      const float bcol = bias[col];
#pragma unroll
      for (int r = 0; r < 4; ++r) {
        const float v = (acc[mi][ni][r] + bcol) * scale;
        const int rr = rbase + r;
        if (MODE == 2) {
          reinterpret_cast<float*>(outp)[(size_t)rr * DMODEL + col] = v;
        } else {
          const int s = rr >> 2, n = rr & 3, h = col >> 6, f = col & 63;
          const int bh = n * NHEAD + h;
          int idx;
          if (MODE == 0) idx = bh * (S_LEN * FDIM) + s * FDIM + f;
          else           idx = bh * (S_LEN * FDIM) + f * S_LEN + s;
          reinterpret_cast<unsigned short*>(outp)[idx] = f2bf(v);
        }
      }
    }
  }
}

// ---------------- flash attention (swapped-QK^T, in-register softmax) ----
// Q: (B, S, F) bf16, pre-scaled by log2(e)/sqrt(F); Kt: (B, S, F) bf16;
// VT: (B, F, S) bf16; ctx: (MROWS, DMODEL) bf16 in (s*4+n, h*64+f) layout.
// mfma(K,Q) gives S^T[kv][q], q = ll lane-local -> scalar m/l per lane.
// PV uses K=16 MFMA whose B-granule (k = lg*4+j) matches P's natural layout
// -> no cross-lane regroup. (Bisect: unconditional rescale + pk2bf, both
// verified in the R8 pass; only the K=16 PV is new.)
__global__ __launch_bounds__(256, 2) void attn_kernel(
    const unsigned short* __restrict__ Q, const unsigned short* __restrict__ Kt,
    const unsigned short* __restrict__ VT, unsigned short* __restrict__ ctx) {
  __shared__ unsigned short Ks[64 * 64];
  __shared__ unsigned short Vs[64 * 64];  // [f][kv]
  // XCD-aware decode: flat = ((b&7)*32 + qt)*8 + (b>>3)  (bijective)
  const int flat = blockIdx.x;
  const int xcd = flat & 7;
  const int idx = flat >> 3;
  const int b = xcd * 8 + (idx >> 5);
  const int qt = idx & 31;
  const int tid = threadIdx.x;
  const int wave = tid >> 6, lane = tid & 63;
  const int lg = lane >> 4, ll = lane & 15;
  const int qrow0 = qt * 64 + wave * 16;

  // Q fragments (B-operand of swapped QK^T)
  s16x8 qf[2];
  {
    const unsigned short* qp =
        &Q[((size_t)b * S_LEN + qrow0 + ll) * FDIM + (lg << 3)];
    qf[0] = *reinterpret_cast<const s16x8*>(qp);
    qf[1] = *reinterpret_cast<const s16x8*>(qp + 32);
  }

  // pre-swizzled per-lane source offset: LDS[row][L] <- glob[row][L ^ swz(row)]
  const unsigned sx =
      (((unsigned)lane & 7u) << 4) ^ (((unsigned)lane >> 3) << 4);
  const char* kbase = (const char*)Kt + (size_t)b * S_LEN * 128;
  const char* vbase = (const char*)VT + (size_t)b * FDIM * (S_LEN * 2);

  float m_run = -1e30f, l_run = 0.f;
  f32x4 o[4] = {};  // O^T[f = ni*16 + lg*4 + r][q = ll]

  for (int kv0 = 0; kv0 < S_LEN; kv0 += 64) {
    // stage K [kv][f] and V [f][kv-chunk] via global_load_lds (direct DMA)
#pragma unroll
    for (int c = 0; c < 2; ++c) {
      const int rb = (wave * 2 + c) * 8;
      GLD16(kbase + ((size_t)(kv0 + rb + (lane >> 3))) * 128 + sx,
            (char*)Ks + rb * 128);
      GLD16(vbase + ((size_t)(rb + (lane >> 3))) * (S_LEN * 2) +
                (size_t)kv0 * 2 + sx,
            (char*)Vs + rb * 128);
    }
    __syncthreads();

    // S^T = K Q^T : sc[ni][r] = S^T[kv = ni*16 + lg*4 + r][q = ll]
    f32x4 sc[4];
#pragma unroll
    for (int ni = 0; ni < 4; ++ni) {
      const int row = ni * 16 + ll;  // kv row of K
      unsigned off0 = (unsigned)((row << 6) + (lg << 3)) * 2u;
      unsigned off1 = off0 + 64u;
      off0 ^= (unsigned)(row & 7) << 4;
      off1 ^= (unsigned)(row & 7) << 4;
      const s16x8 kb0 = *reinterpret_cast<const s16x8*>(
          reinterpret_cast<const char*>(Ks) + off0);
      const s16x8 kb1 = *reinterpret_cast<const s16x8*>(
          reinterpret_cast<const char*>(Ks) + off1);
      f32x4 z = {};
      z = __builtin_amdgcn_mfma_f32_16x16x32_bf16(kb0, qf[0], z, 0, 0, 0);
      sc[ni] = __builtin_amdgcn_mfma_f32_16x16x32_bf16(kb1, qf[1], z, 0, 0, 0);
    }

    // ---- in-register online softmax (scalar m/l per lane; q = ll) ----
    float pm0 = fmaxf(fmaxf(sc[0][0], sc[0][1]), fmaxf(sc[0][2], sc[0][3]));
    float pm1 = fmaxf(fmaxf(sc[1][0], sc[1][1]), fmaxf(sc[1][2], sc[1][3]));
    float pm2 = fmaxf(fmaxf(sc[2][0], sc[2][1]), fmaxf(sc[2][2], sc[2][3]));
    float pm3 = fmaxf(fmaxf(sc[3][0], sc[3][1]), fmaxf(sc[3][2], sc[3][3]));
    float pm = fmaxf(fmaxf(pm0, pm1), fmaxf(pm2, pm3));
    pm = fmaxf(pm, __shfl_xor(pm, 16, 64));
    pm = fmaxf(pm, __shfl_xor(pm, 32, 64));
    const float mn = fmaxf(m_run, pm);
    const float fac = exp2f(m_run - mn);
    m_run = mn;

    float rs = 0.f;
#pragma unroll
    for (int ni = 0; ni < 4; ++ni)
#pragma unroll
      for (int r = 0; r < 4; ++r) {
        const float p = exp2f(sc[ni][r] - mn);
        sc[ni][r] = p;
        rs += p;
      }
    rs += __shfl_xor(rs, 16, 64);
    rs += __shfl_xor(rs, 32, 64);
    l_run = l_run * fac + rs;
#pragma unroll
    for (int ni = 0; ni < 4; ++ni)
#pragma unroll
      for (int r = 0; r < 4; ++r) o[ni][r] *= fac;

    // O^T += V^T P, per 16-kv chunk c: B-frag = P granule already in-lane
#pragma unroll
    for (int c = 0; c < 4; ++c) {
      union { s16x4 v; unsigned u[2]; } pb;
      pb.u[0] = pk2bf(sc[c][0], sc[c][1]);
      pb.u[1] = pk2bf(sc[c][2], sc[c][3]);
#pragma unroll
      for (int ni = 0; ni < 4; ++ni) {
        const int row = ni * 16 + ll;  // f row in Vs
        unsigned off = (unsigned)((row << 6) + c * 16 + (lg << 2)) * 2u;
        off ^= (unsigned)(row & 7) << 4;
        const s16x4 vb = *reinterpret_cast<const s16x4*>(
            reinterpret_cast<const char*>(Vs) + off);
        o[ni] = __builtin_amdgcn_mfma_f32_16x16x16bf16_1k(vb, pb.v, o[ni],
                                                          0, 0, 0);
      }
    }
    __syncthreads();
  }

  // normalize + write ctx (bf16): q = qrow0 + ll, f = ni*16 + lg*4 + r
  const int n = b >> 4, h = b & 15;
  const float inv = 1.f / l_run;
  const int s = qrow0 + ll;
  unsigned short* crow = ctx + (size_t)(s * NBATCH + n) * DMODEL + h * FDIM;
#pragma unroll
  for (int ni = 0; ni < 4; ++ni) {
    ushort4 w;
    w.x = f2bf(o[ni][0] * inv);
    w.y = f2bf(o[ni][1] * inv);
    w.z = f2bf(o[ni][2] * inv);
    w.w = f2bf(o[ni][3] * inv);
    *reinterpret_cast<ushort4*>(crow + ni * 16 + lg * 4) = w;
  }
}

extern "C" void kernel_launch(void* const* d_in, const int* in_sizes, int n_in,
                              void* d_out, int out_size, void* d_ws,
                              size_t ws_size, hipStream_t stream) {
  const float* query = (const float*)d_in[0];
  const float* key_t = (const float*)d_in[1];
  const float* value = (const float*)d_in[2];
  const float* wq_w = (const float*)d_in[3];
  const float* wq_b = (const float*)d_in[4];
  const float* wk_w = (const float*)d_in[5];
  const float* wk_b = (const float*)d_in[6];
  const float* wv_w = (const float*)d_in[7];
  const float* wv_b = (const float*)d_in[8];
  const float* wo_w = (const float*)d_in[9];
  const float* wo_b = (const float*)d_in[10];

  char* ws = (char*)d_ws;
  unsigned short* wtq = (unsigned short*)(ws + (0ull << 20));
  unsigned short* wtk = (unsigned short*)(ws + (2ull << 20));
  unsigned short* wtv = (unsigned short*)(ws + (4ull << 20));
  unsigned short* wto = (unsigned short*)(ws + (6ull << 20));
  unsigned short* cbuf = (unsigned short*)(ws + (8ull << 20));   // 16 MB, reused
  unsigned short* qa = (unsigned short*)(ws + (24ull << 20));
  unsigned short* ka = (unsigned short*)(ws + (40ull << 20));
  unsigned short* va = (unsigned short*)(ws + (56ull << 20));
  unsigned short* ctx = (unsigned short*)(ws + (72ull << 20));   // 16 MB bf16

  const dim3 blk(256);
  const dim3 tgrid(32, 32);
  hipLaunchKernelGGL(transpose_w_kernel, tgrid, blk, 0, stream, wq_w, wtq);
  hipLaunchKernelGGL(transpose_w_kernel, tgrid, blk, 0, stream, wk_w, wtk);
  hipLaunchKernelGGL(transpose_w_kernel, tgrid, blk, 0, stream, wv_w, wtv);
  hipLaunchKernelGGL(transpose_w_kernel, tgrid, blk, 0, stream, wo_w, wto);

  const dim3 ggrid(MROWS / 128, DMODEL / 128);
  const dim3 cgrid(4096);

  // Q pre-scale folds 1/sqrt(F) AND log2(e): softmax done in base-2 domain.
  const float qscale = 0.125f * 1.44269504088896340736f;

  hipLaunchKernelGGL(convert_kernel, cgrid, blk, 0, stream, query, cbuf);
  hipLaunchKernelGGL((gemm_kernel<0>), ggrid, blk, 0, stream, cbuf, wtq, wq_b,
                     (void*)qa, qscale);
  hipLaunchKernelGGL(convert_kernel, cgrid, blk, 0, stream, key_t, cbuf);
  hipLaunchKernelGGL((gemm_kernel<0>), ggrid, blk, 0, stream, cbuf, wtk, wk_b,
                     (void*)ka, 1.0f);
  hipLaunchKernelGGL(convert_kernel, cgrid, blk, 0, stream, value, cbuf);
  hipLaunchKernelGGL((gemm_kernel<1>), ggrid, blk, 0, stream, cbuf, wtv, wv_b,
                     (void*)va, 1.0f);

  const dim3 agrid(S_LEN / 64 * BHEADS);  // 2048 flat, XCD-decoded in-kernel
  hipLaunchKernelGGL(attn_kernel, agrid, blk, 0, stream, qa, ka, va, ctx);

  hipLaunchKernelGGL((gemm_kernel<2>), ggrid, blk, 0, stream, ctx, wto, wo_b,
                     d_out, 1.0f);
}